// Round 1
// baseline (354.094 us; speedup 1.0000x reference)
//
#include <hip/hip_runtime.h>
#include <math.h>

// Problem constants
#define BATCH 8192
#define HD    256
#define NPTS  51              // nb_steps=50 -> 51 quadrature points
#define MTOT  (BATCH*NPTS)    // 417792 = 64 * 6528

typedef __bf16 bf16x8 __attribute__((ext_vector_type(8)));
typedef float  f32x4  __attribute__((ext_vector_type(4)));

// ---- workspace layout (bytes), all offsets 256B-aligned ----
#define OFF_IW2B  0            // 65536 ushort (bf16 iw2, row-major [n][k])
#define OFF_NW2B  131072       // 65536 ushort (bf16 nw2)
#define OFF_W1X   262144       // 256 f32   (iw1[:,0])
#define OFF_CC    263168       // 64 f32    (CC quadrature weights)
#define OFF_STEPS 263424       // 64 f32    (cos nodes)
#define OFF_ACCB  263680       // 8192 f32  (sum_p f*cc per batch)
#define OFF_OFFS  296448       // 8192 f32
#define OFF_SCAL  329216       // 8192 f32
#define OFF_NW1P  361984       // 256*16 f32 (nw1 padded to 16 cols)
#define OFF_G1    378368       // 8192*256 f32 (h-part of layer1 + ib1)
#define OFF_A1N   8766976      // 8192*256 ushort (bf16 relu(h@nw1.T+nb1))

__device__ __forceinline__ unsigned short f2bf(float f) {
    union { float f; unsigned u; } v; v.f = f;
    unsigned r = v.u + 0x7FFFu + ((v.u >> 16) & 1u);   // RTNE
    return (unsigned short)(r >> 16);
}

// ---------------- k0: prep (weights->bf16, CC weights, zero accb) ----------------
__global__ void k0_prep(const float* __restrict__ iw2, const float* __restrict__ nw2,
                        const float* __restrict__ nw1, const float* __restrict__ iw1,
                        unsigned short* iw2b, unsigned short* nw2b, float* w1xs,
                        float* cc, float* steps, float* accb, float* nw1p) {
    int blk = blockIdx.x, tid = threadIdx.x;
    if (blk < 256) {
        int t = blk * 256 + tid;
        iw2b[t] = f2bf(iw2[t]);
        nw2b[t] = f2bf(nw2[t]);
    } else if (blk < 288) {
        int t = (blk - 256) * 256 + tid;
        accb[t] = 0.f;
        if (blk == 256) w1xs[tid] = iw1[tid * 16];   // column 0 of iw1
    } else if (blk == 288) {
        for (int j = 0; j < 16; ++j)
            nw1p[tid * 16 + j] = (j < 15) ? nw1[tid * 15 + j] : 0.f;
    } else {
        // Clenshaw-Curtis weights, double precision, matching reference _cc_weights
        const double PI_D = 3.14159265358979323846264338327950288;
        if (tid <= 50) {
            int j = tid;
            double s = 0.0;
            for (int i = 0; i <= 50; i += 2) {          // odd i have W=0
                double w = (i == 0) ? 1.0 : 2.0 / (1.0 - (double)(i * i));
                double l;
                if (j == 0)       l = 0.5;              // lam[:,0] = 0.5 (pre-scale)
                else if (j == 50) l = 0.5;              // 0.5*cos(i*pi), i even -> 0.5
                else              l = cos((double)i * (double)j * PI_D / 50.0);
                s += l * w;
            }
            cc[j]    = (float)(s * 2.0 / 50.0);
            steps[j] = (float)cos((double)j * PI_D / 50.0);
        }
    }
}

// ---------------- k1: per-batch precompute (4 batches/block) ----------------
__global__ void k1_pre(const float* __restrict__ h, const float* __restrict__ iw1,
                       const float* __restrict__ ib1, const float* __restrict__ nw1p,
                       const float* __restrict__ nb1,
                       float* __restrict__ g1, unsigned short* __restrict__ a1n) {
    __shared__ float hs[4][15];
    int b0 = blockIdx.x * 4, tid = threadIdx.x, n = tid;
    if (tid < 60) { int bb = tid / 15, j = tid % 15; hs[bb][j] = h[(b0 + bb) * 15 + j]; }
    __syncthreads();
    float ir[16], nr[16];
    const float4* ip  = (const float4*)(iw1  + n * 16);
    const float4* npt = (const float4*)(nw1p + n * 16);
    ((float4*)ir)[0] = ip[0];  ((float4*)ir)[1] = ip[1];
    ((float4*)ir)[2] = ip[2];  ((float4*)ir)[3] = ip[3];
    ((float4*)nr)[0] = npt[0]; ((float4*)nr)[1] = npt[1];
    ((float4*)nr)[2] = npt[2]; ((float4*)nr)[3] = npt[3];
    float bi = ib1[n], bn = nb1[n];
    for (int bb = 0; bb < 4; ++bb) {
        float g = bi, a = bn;
        #pragma unroll
        for (int j = 0; j < 15; ++j) { float hv = hs[bb][j]; g += hv * ir[j + 1]; a += hv * nr[j]; }
        int b = b0 + bb;
        g1[b * 256 + n]  = g;                       // no relu: x-part added later
        a1n[b * 256 + n] = f2bf(fmaxf(a, 0.f));
    }
}

// ---------------- k2: main integrand GEMM (64 rows x 256 out, K=256) ----------------
__launch_bounds__(256, 3)
__global__ void k2_main(const float* __restrict__ x, const float* __restrict__ g1,
                        const float* __restrict__ w1xs, const unsigned short* __restrict__ iw2b,
                        const float* __restrict__ ib2, const float* __restrict__ iw3,
                        const float* __restrict__ ib3, const float* __restrict__ cc,
                        const float* __restrict__ steps, float* __restrict__ accb) {
    __shared__ unsigned short As[64 * 264];   // 64 rows x 256 k, pad 8 -> 33792 B
    __shared__ float Pp[4 * 64];              // per-wave partial layer3 dots
    int tid = threadIdx.x;
    int m0 = blockIdx.x * 64;

    // ---- stage A tile: a1[r,k] = relu(g1[b,k] + xs * w1x[k]) as bf16 ----
    {
        int r = tid >> 2, kq = (tid & 3) * 64;
        int m = m0 + r, b = m / 51, p = m - b * 51;
        float xs = x[b] * (steps[p] + 1.f) * 0.5f;
        const float* gp = g1 + b * 256;
        #pragma unroll
        for (int kk = 0; kk < 64; kk += 4) {
            int k = kq + kk;
            float4 g  = *(const float4*)(gp + k);
            float4 wv = *(const float4*)(w1xs + k);
            ushort4 o;
            o.x = f2bf(fmaxf(g.x + xs * wv.x, 0.f));
            o.y = f2bf(fmaxf(g.y + xs * wv.y, 0.f));
            o.z = f2bf(fmaxf(g.z + xs * wv.z, 0.f));
            o.w = f2bf(fmaxf(g.w + xs * wv.w, 0.f));
            *(ushort4*)&As[r * 264 + k] = o;
        }
    }
    __syncthreads();

    int lane = tid & 63, w = tid >> 6, l16 = lane & 15, quad = lane >> 4;

    f32x4 acc[4][4];
    #pragma unroll
    for (int mt = 0; mt < 4; ++mt)
        #pragma unroll
        for (int nt = 0; nt < 4; ++nt)
            acc[mt][nt] = (f32x4){0.f, 0.f, 0.f, 0.f};

    #pragma unroll
    for (int ks = 0; ks < 8; ++ks) {
        bf16x8 af[4], bfr[4];
        #pragma unroll
        for (int mt = 0; mt < 4; ++mt)
            af[mt] = *(const bf16x8*)&As[(mt * 16 + l16) * 264 + ks * 32 + quad * 8];
        #pragma unroll
        for (int nt = 0; nt < 4; ++nt) {
            int n = w * 64 + nt * 16 + l16;
            bfr[nt] = *(const bf16x8*)(iw2b + n * 256 + ks * 32 + quad * 8);
        }
        #pragma unroll
        for (int mt = 0; mt < 4; ++mt)
            #pragma unroll
            for (int nt = 0; nt < 4; ++nt)
                acc[mt][nt] = __builtin_amdgcn_mfma_f32_16x16x32_bf16(af[mt], bfr[nt], acc[mt][nt], 0, 0, 0);
    }

    // ---- epilogue: relu(+ib2), dot with iw3, reduce over n ----
    float pf[4][4] = {};
    #pragma unroll
    for (int nt = 0; nt < 4; ++nt) {
        int n = w * 64 + nt * 16 + l16;
        float bias = ib2[n], w3 = iw3[n];
        #pragma unroll
        for (int mt = 0; mt < 4; ++mt)
            #pragma unroll
            for (int i = 0; i < 4; ++i) {
                float v = acc[mt][nt][i] + bias;
                v = v > 0.f ? v : 0.f;
                pf[mt][i] += v * w3;
            }
    }
    #pragma unroll
    for (int mask = 1; mask < 16; mask <<= 1)
        #pragma unroll
        for (int mt = 0; mt < 4; ++mt)
            #pragma unroll
            for (int i = 0; i < 4; ++i)
                pf[mt][i] += __shfl_xor(pf[mt][i], mask, 64);
    if (l16 == 0) {
        #pragma unroll
        for (int mt = 0; mt < 4; ++mt)
            #pragma unroll
            for (int i = 0; i < 4; ++i)
                Pp[w * 64 + mt * 16 + quad * 4 + i] = pf[mt][i];
    }
    __syncthreads();
    if (tid < 64) {
        float s = Pp[tid] + Pp[64 + tid] + Pp[128 + tid] + Pp[192 + tid] + ib3[0];
        float f = s > 0.f ? s + 1.f : __expf(s);        // elu(s)+1
        int m = m0 + tid, b = m / 51, p = m - b * 51;
        atomicAdd(&accb[b], f * cc[p]);
    }
}

// ---------------- k3: second network (offset/scaling), 64 batches/block ----------------
__launch_bounds__(256, 3)
__global__ void k3_nnet(const unsigned short* __restrict__ a1n, const unsigned short* __restrict__ nw2b,
                        const float* __restrict__ nb2, const float* __restrict__ nw3,
                        const float* __restrict__ nb3, float* __restrict__ offs,
                        float* __restrict__ scal) {
    __shared__ float Pp[4 * 2 * 64];
    int tid = threadIdx.x;
    int m0 = blockIdx.x * 64;
    int lane = tid & 63, w = tid >> 6, l16 = lane & 15, quad = lane >> 4;

    f32x4 acc[4][4];
    #pragma unroll
    for (int mt = 0; mt < 4; ++mt)
        #pragma unroll
        for (int nt = 0; nt < 4; ++nt)
            acc[mt][nt] = (f32x4){0.f, 0.f, 0.f, 0.f};

    #pragma unroll
    for (int ks = 0; ks < 8; ++ks) {
        bf16x8 af[4], bfr[4];
        #pragma unroll
        for (int mt = 0; mt < 4; ++mt)
            af[mt] = *(const bf16x8*)(a1n + (m0 + mt * 16 + l16) * 256 + ks * 32 + quad * 8);
        #pragma unroll
        for (int nt = 0; nt < 4; ++nt)
            bfr[nt] = *(const bf16x8*)(nw2b + (w * 64 + nt * 16 + l16) * 256 + ks * 32 + quad * 8);
        #pragma unroll
        for (int mt = 0; mt < 4; ++mt)
            #pragma unroll
            for (int nt = 0; nt < 4; ++nt)
                acc[mt][nt] = __builtin_amdgcn_mfma_f32_16x16x32_bf16(af[mt], bfr[nt], acc[mt][nt], 0, 0, 0);
    }

    float p0[4][4] = {}, p1[4][4] = {};
    #pragma unroll
    for (int nt = 0; nt < 4; ++nt) {
        int n = w * 64 + nt * 16 + l16;
        float bias = nb2[n], wa = nw3[n], wb = nw3[256 + n];
        #pragma unroll
        for (int mt = 0; mt < 4; ++mt)
            #pragma unroll
            for (int i = 0; i < 4; ++i) {
                float v = acc[mt][nt][i] + bias;
                v = v > 0.f ? v : 0.f;
                p0[mt][i] += v * wa;
                p1[mt][i] += v * wb;
            }
    }
    #pragma unroll
    for (int mask = 1; mask < 16; mask <<= 1)
        #pragma unroll
        for (int mt = 0; mt < 4; ++mt)
            #pragma unroll
            for (int i = 0; i < 4; ++i) {
                p0[mt][i] += __shfl_xor(p0[mt][i], mask, 64);
                p1[mt][i] += __shfl_xor(p1[mt][i], mask, 64);
            }
    if (l16 == 0) {
        #pragma unroll
        for (int mt = 0; mt < 4; ++mt)
            #pragma unroll
            for (int i = 0; i < 4; ++i) {
                int r = mt * 16 + quad * 4 + i;
                Pp[w * 128 + r]      = p0[mt][i];
                Pp[w * 128 + 64 + r] = p1[mt][i];
            }
    }
    __syncthreads();
    if (tid < 64) {
        float s0 = Pp[tid]      + Pp[128 + tid] + Pp[256 + tid] + Pp[384 + tid] + nb3[0];
        float s1 = Pp[64 + tid] + Pp[192 + tid] + Pp[320 + tid] + Pp[448 + tid] + nb3[1];
        offs[m0 + tid] = s0;
        scal[m0 + tid] = __expf(s1);
    }
}

// ---------------- k4: combine ----------------
__global__ void k4_final(const float* __restrict__ x, const float* __restrict__ accb,
                         const float* __restrict__ offs, const float* __restrict__ scal,
                         float* __restrict__ out) {
    int i = blockIdx.x * 256 + threadIdx.x;
    out[i] = scal[i] * (0.5f * x[i] * accb[i]) + offs[i];
}

extern "C" void kernel_launch(void* const* d_in, const int* in_sizes, int n_in,
                              void* d_out, int out_size, void* d_ws, size_t ws_size,
                              hipStream_t stream) {
    const float* x   = (const float*)d_in[0];
    const float* h   = (const float*)d_in[1];
    const float* iw1 = (const float*)d_in[2];
    const float* ib1 = (const float*)d_in[3];
    const float* iw2 = (const float*)d_in[4];
    const float* ib2 = (const float*)d_in[5];
    const float* iw3 = (const float*)d_in[6];
    const float* ib3 = (const float*)d_in[7];
    const float* nw1 = (const float*)d_in[8];
    const float* nb1 = (const float*)d_in[9];
    const float* nw2 = (const float*)d_in[10];
    const float* nb2 = (const float*)d_in[11];
    const float* nw3 = (const float*)d_in[12];
    const float* nb3 = (const float*)d_in[13];
    float* out = (float*)d_out;

    char* ws = (char*)d_ws;
    unsigned short* iw2b = (unsigned short*)(ws + OFF_IW2B);
    unsigned short* nw2b = (unsigned short*)(ws + OFF_NW2B);
    float* w1xs  = (float*)(ws + OFF_W1X);
    float* cc    = (float*)(ws + OFF_CC);
    float* steps = (float*)(ws + OFF_STEPS);
    float* accb  = (float*)(ws + OFF_ACCB);
    float* offs  = (float*)(ws + OFF_OFFS);
    float* scal  = (float*)(ws + OFF_SCAL);
    float* nw1p  = (float*)(ws + OFF_NW1P);
    float* g1    = (float*)(ws + OFF_G1);
    unsigned short* a1n = (unsigned short*)(ws + OFF_A1N);

    k0_prep<<<dim3(290), dim3(256), 0, stream>>>(iw2, nw2, nw1, iw1, iw2b, nw2b, w1xs,
                                                 cc, steps, accb, nw1p);
    k1_pre<<<dim3(BATCH / 4), dim3(256), 0, stream>>>(h, iw1, ib1, nw1p, nb1, g1, a1n);
    k2_main<<<dim3(MTOT / 64), dim3(256), 0, stream>>>(x, g1, w1xs, iw2b, ib2, iw3, ib3,
                                                       cc, steps, accb);
    k3_nnet<<<dim3(BATCH / 64), dim3(256), 0, stream>>>(a1n, nw2b, nb2, nw3, nb3, offs, scal);
    k4_final<<<dim3(BATCH / 256), dim3(256), 0, stream>>>(x, accb, offs, scal, out);
}

// Round 3
// 243.495 us; speedup vs baseline: 1.4542x; 1.4542x over previous
//
#include <hip/hip_runtime.h>
#include <hip/hip_bf16.h>
#include <math.h>

// Problem constants
#define BATCH 8192
#define HD    256
#define NPTS  51              // nb_steps=50 -> 51 quadrature points
#define MTOT  (BATCH*NPTS)    // 417792 = 128 * 3264

typedef __bf16 bf16x8 __attribute__((ext_vector_type(8)));
typedef float  f32x4  __attribute__((ext_vector_type(4)));

// ---- workspace layout (bytes) ----
#define OFF_IW2B  0            // 65536 ushort (bf16 iw2, row-major [n][k])
#define OFF_NW2B  131072       // 65536 ushort (bf16 nw2)
#define OFF_W1X   262144       // 256 f32   (iw1[:,0])
#define OFF_CC    263168       // 64 f32    (CC quadrature weights)
#define OFF_STEPS 263424       // 64 f32    (cos nodes)
#define OFF_OFFS  263680       // 8192 f32
#define OFF_SCAL  296448       // 8192 f32
#define OFF_NW1P  329216       // 256*16 f32 (nw1 padded to 16 cols)
#define OFF_G1    345600       // 8192*256 f32 (h-part of layer1 + ib1)
#define OFF_A1N   8734208      // 8192*256 ushort (bf16 relu(h@nw1.T+nb1))
#define OFF_FVALS OFF_A1N      // 417792 f32 — ALIASES a1n: k3 (reader of a1n) runs BEFORE k2 (writer of fvals)

__device__ __forceinline__ unsigned short f2bf(float f) {
    union { float f; unsigned u; } v; v.f = f;
    unsigned r = v.u + 0x7FFFu + ((v.u >> 16) & 1u);   // RTNE
    return (unsigned short)(r >> 16);
}

__device__ __forceinline__ unsigned pk2bf(float lo, float hi) {
    __hip_bfloat162 t = __float22bfloat162_rn(float2{lo, hi});
    union { __hip_bfloat162 b; unsigned u; } v; v.b = t;
    return v.u;
}

// ---------------- k0: prep (weights->bf16, CC weights) ----------------
__global__ void k0_prep(const float* __restrict__ iw2, const float* __restrict__ nw2,
                        const float* __restrict__ nw1, const float* __restrict__ iw1,
                        unsigned short* iw2b, unsigned short* nw2b, float* w1xs,
                        float* cc, float* steps, float* nw1p) {
    int blk = blockIdx.x, tid = threadIdx.x;
    if (blk < 256) {
        int t = blk * 256 + tid;
        iw2b[t] = f2bf(iw2[t]);
        nw2b[t] = f2bf(nw2[t]);
    } else if (blk == 256) {
        w1xs[tid] = iw1[tid * 16];   // column 0 of iw1
    } else if (blk == 257) {
        for (int j = 0; j < 16; ++j)
            nw1p[tid * 16 + j] = (j < 15) ? nw1[tid * 15 + j] : 0.f;
    } else {
        // Clenshaw-Curtis weights, double precision, matching reference _cc_weights
        const double PI_D = 3.14159265358979323846264338327950288;
        if (tid <= 50) {
            int j = tid;
            double s = 0.0;
            for (int i = 0; i <= 50; i += 2) {          // odd i have W=0
                double w = (i == 0) ? 1.0 : 2.0 / (1.0 - (double)(i * i));
                double l;
                if (j == 0)       l = 0.5;              // lam[:,0] = 0.5
                else if (j == 50) l = 0.5;              // 0.5*cos(i*pi), i even -> 0.5
                else              l = cos((double)i * (double)j * PI_D / 50.0);
                s += l * w;
            }
            cc[j]    = (float)(s * 2.0 / 50.0);
            steps[j] = (float)cos((double)j * PI_D / 50.0);
        }
    }
}

// ---------------- k1: per-batch precompute (4 batches/block) ----------------
__global__ void k1_pre(const float* __restrict__ h, const float* __restrict__ iw1,
                       const float* __restrict__ ib1, const float* __restrict__ nw1p,
                       const float* __restrict__ nb1,
                       float* __restrict__ g1, unsigned short* __restrict__ a1n) {
    __shared__ float hs[4][15];
    int b0 = blockIdx.x * 4, tid = threadIdx.x, n = tid;
    if (tid < 60) { int bb = tid / 15, j = tid % 15; hs[bb][j] = h[(b0 + bb) * 15 + j]; }
    __syncthreads();
    float ir[16], nr[16];
    const float4* ip  = (const float4*)(iw1  + n * 16);
    const float4* npt = (const float4*)(nw1p + n * 16);
    ((float4*)ir)[0] = ip[0];  ((float4*)ir)[1] = ip[1];
    ((float4*)ir)[2] = ip[2];  ((float4*)ir)[3] = ip[3];
    ((float4*)nr)[0] = npt[0]; ((float4*)nr)[1] = npt[1];
    ((float4*)nr)[2] = npt[2]; ((float4*)nr)[3] = npt[3];
    float bi = ib1[n], bn = nb1[n];
    for (int bb = 0; bb < 4; ++bb) {
        float g = bi, a = bn;
        #pragma unroll
        for (int j = 0; j < 15; ++j) { float hv = hs[bb][j]; g += hv * ir[j + 1]; a += hv * nr[j]; }
        int b = b0 + bb;
        g1[b * 256 + n]  = g;                       // no relu: x-part added later
        a1n[b * 256 + n] = f2bf(fmaxf(a, 0.f));
    }
}

// ---------------- k2: main integrand GEMM (128 rows x 256 out, K=256) ----------------
// As layout: 128 rows x 32 chunks of 8 bf16 (16B); chunk c of row r stored at
// physical chunk c ^ (r&7)  -> 8 lanes/bank-group floor for all b128 LDS ops.
// Waves: 2x2 (mw = wave&1 owns 64 rows, nw = wave>>1 owns 128 cols).
__launch_bounds__(256, 2)
__global__ void k2_main(const float* __restrict__ x, const float* __restrict__ g1,
                        const float* __restrict__ w1xs, const unsigned short* __restrict__ iw2b,
                        const float* __restrict__ ib2, const float* __restrict__ iw3,
                        const float* __restrict__ ib3, const float* __restrict__ cc,
                        const float* __restrict__ steps, float* __restrict__ fvals) {
    __shared__ __align__(16) unsigned char smem[65536];
    unsigned short* As = (unsigned short*)smem;          // 128 x 256 bf16, swizzled
    float*          Pp = (float*)smem;                   // aliased after K-loop: 128 x 36 f32

    int tid = threadIdx.x;
    int m0 = blockIdx.x * 128;

    // ---- stage A tile: thread owns chunk c (8 k-elems) for 16 consecutive rows ----
    {
        int g = tid >> 5;            // row group 0..7
        int c = tid & 31;            // k-chunk 0..31
        int m = m0 + g * 16;
        int b = m / 51;
        int p = m - b * 51;
        const float* gp = g1 + b * 256 + c * 8;
        float4 ga = ((const float4*)gp)[0];
        float4 gb = ((const float4*)gp)[1];
        float4 wa = ((const float4*)(w1xs + c * 8))[0];
        float4 wb = ((const float4*)(w1xs + c * 8))[1];
        float xb = x[b];
        #pragma unroll
        for (int rr = 0; rr < 16; ++rr) {
            if (p == 51) {
                p = 0; ++b;
                gp = g1 + b * 256 + c * 8;
                ga = ((const float4*)gp)[0];
                gb = ((const float4*)gp)[1];
                xb = x[b];
            }
            float xs = xb * (steps[p] + 1.f) * 0.5f;
            ++p;
            float a0 = fmaxf(ga.x + xs * wa.x, 0.f);
            float a1 = fmaxf(ga.y + xs * wa.y, 0.f);
            float a2 = fmaxf(ga.z + xs * wa.z, 0.f);
            float a3 = fmaxf(ga.w + xs * wa.w, 0.f);
            float a4 = fmaxf(gb.x + xs * wb.x, 0.f);
            float a5 = fmaxf(gb.y + xs * wb.y, 0.f);
            float a6 = fmaxf(gb.z + xs * wb.z, 0.f);
            float a7 = fmaxf(gb.w + xs * wb.w, 0.f);
            uint4 o;
            o.x = pk2bf(a0, a1); o.y = pk2bf(a2, a3);
            o.z = pk2bf(a4, a5); o.w = pk2bf(a6, a7);
            int r = g * 16 + rr;
            int pc = c ^ (r & 7);
            *(uint4*)(As + r * 256 + pc * 8) = o;
        }
    }
    __syncthreads();

    int lane = tid & 63, w = tid >> 6;
    int mw = w & 1, nw = w >> 1;
    int l16 = lane & 15, quad = lane >> 4, l7 = l16 & 7;

    f32x4 acc[4][8];
    #pragma unroll
    for (int mt = 0; mt < 4; ++mt)
        #pragma unroll
        for (int nt = 0; nt < 8; ++nt)
            acc[mt][nt] = (f32x4){0.f, 0.f, 0.f, 0.f};

    #pragma unroll
    for (int ks = 0; ks < 8; ++ks) {
        bf16x8 af[4], bfr[8];
        #pragma unroll
        for (int mt = 0; mt < 4; ++mt) {
            int rA = mw * 64 + mt * 16 + l16;
            int pc = (ks * 4 + quad) ^ l7;
            af[mt] = *(const bf16x8*)(As + rA * 256 + pc * 8);
        }
        #pragma unroll
        for (int nt = 0; nt < 8; ++nt) {
            int n = nw * 128 + nt * 16 + l16;
            bfr[nt] = *(const bf16x8*)(iw2b + n * 256 + ks * 32 + quad * 8);
        }
        #pragma unroll
        for (int mt = 0; mt < 4; ++mt)
            #pragma unroll
            for (int nt = 0; nt < 8; ++nt)
                acc[mt][nt] = __builtin_amdgcn_mfma_f32_16x16x32_bf16(af[mt], bfr[nt], acc[mt][nt], 0, 0, 0);
    }

    // ---- epilogue: relu(+ib2), dot with iw3 over this wave's 128 n-cols ----
    float pf[4][4];
    #pragma unroll
    for (int mt = 0; mt < 4; ++mt)
        #pragma unroll
        for (int i = 0; i < 4; ++i) pf[mt][i] = 0.f;
    #pragma unroll
    for (int nt = 0; nt < 8; ++nt) {
        int n = nw * 128 + nt * 16 + l16;
        float bias = ib2[n], w3 = iw3[n];
        #pragma unroll
        for (int mt = 0; mt < 4; ++mt)
            #pragma unroll
            for (int i = 0; i < 4; ++i) {
                float v = acc[mt][nt][i] + bias;
                v = v > 0.f ? v : 0.f;
                pf[mt][i] += v * w3;
            }
    }
    __syncthreads();     // all As reads done; smem becomes Pp
    #pragma unroll
    for (int mt = 0; mt < 4; ++mt)
        #pragma unroll
        for (int i = 0; i < 4; ++i) {
            int row = mw * 64 + mt * 16 + quad * 4 + i;
            Pp[row * 36 + nw * 16 + l16] = pf[mt][i];
        }
    __syncthreads();
    {
        int row = tid >> 1, half = tid & 1;
        const float4* pp = (const float4*)(Pp + row * 36 + half * 16);
        float4 v0 = pp[0], v1 = pp[1], v2 = pp[2], v3 = pp[3];
        float s = v0.x + v0.y + v0.z + v0.w + v1.x + v1.y + v1.z + v1.w
                + v2.x + v2.y + v2.z + v2.w + v3.x + v3.y + v3.z + v3.w;
        s += __shfl_xor(s, 1, 64);
        if (!half) {
            int m = m0 + row;
            int p = m % 51;
            float sv = s + ib3[0];
            float f = sv > 0.f ? sv + 1.f : __expf(sv);   // elu(sv)+1
            fvals[m] = f * cc[p];
        }
    }
}

// ---------------- k3: second network (offset/scaling), 64 batches/block ----------------
__launch_bounds__(256, 3)
__global__ void k3_nnet(const unsigned short* __restrict__ a1n, const unsigned short* __restrict__ nw2b,
                        const float* __restrict__ nb2, const float* __restrict__ nw3,
                        const float* __restrict__ nb3, float* __restrict__ offs,
                        float* __restrict__ scal) {
    __shared__ float Pp[4 * 2 * 64];
    int tid = threadIdx.x;
    int m0 = blockIdx.x * 64;
    int lane = tid & 63, w = tid >> 6, l16 = lane & 15, quad = lane >> 4;

    f32x4 acc[4][4];
    #pragma unroll
    for (int mt = 0; mt < 4; ++mt)
        #pragma unroll
        for (int nt = 0; nt < 4; ++nt)
            acc[mt][nt] = (f32x4){0.f, 0.f, 0.f, 0.f};

    #pragma unroll
    for (int ks = 0; ks < 8; ++ks) {
        bf16x8 af[4], bfr[4];
        #pragma unroll
        for (int mt = 0; mt < 4; ++mt)
            af[mt] = *(const bf16x8*)(a1n + (m0 + mt * 16 + l16) * 256 + ks * 32 + quad * 8);
        #pragma unroll
        for (int nt = 0; nt < 4; ++nt)
            bfr[nt] = *(const bf16x8*)(nw2b + (w * 64 + nt * 16 + l16) * 256 + ks * 32 + quad * 8);
        #pragma unroll
        for (int mt = 0; mt < 4; ++mt)
            #pragma unroll
            for (int nt = 0; nt < 4; ++nt)
                acc[mt][nt] = __builtin_amdgcn_mfma_f32_16x16x32_bf16(af[mt], bfr[nt], acc[mt][nt], 0, 0, 0);
    }

    float p0[4][4] = {}, p1[4][4] = {};
    #pragma unroll
    for (int nt = 0; nt < 4; ++nt) {
        int n = w * 64 + nt * 16 + l16;
        float bias = nb2[n], wa = nw3[n], wb = nw3[256 + n];
        #pragma unroll
        for (int mt = 0; mt < 4; ++mt)
            #pragma unroll
            for (int i = 0; i < 4; ++i) {
                float v = acc[mt][nt][i] + bias;
                v = v > 0.f ? v : 0.f;
                p0[mt][i] += v * wa;
                p1[mt][i] += v * wb;
            }
    }
    #pragma unroll
    for (int mask = 1; mask < 16; mask <<= 1)
        #pragma unroll
        for (int mt = 0; mt < 4; ++mt)
            #pragma unroll
            for (int i = 0; i < 4; ++i) {
                p0[mt][i] += __shfl_xor(p0[mt][i], mask, 64);
                p1[mt][i] += __shfl_xor(p1[mt][i], mask, 64);
            }
    if (l16 == 0) {
        #pragma unroll
        for (int mt = 0; mt < 4; ++mt)
            #pragma unroll
            for (int i = 0; i < 4; ++i) {
                int r = mt * 16 + quad * 4 + i;
                Pp[w * 128 + r]      = p0[mt][i];
                Pp[w * 128 + 64 + r] = p1[mt][i];
            }
    }
    __syncthreads();
    if (tid < 64) {
        float s0 = Pp[tid]      + Pp[128 + tid] + Pp[256 + tid] + Pp[384 + tid] + nb3[0];
        float s1 = Pp[64 + tid] + Pp[192 + tid] + Pp[320 + tid] + Pp[448 + tid] + nb3[1];
        offs[m0 + tid] = s0;
        scal[m0 + tid] = __expf(s1);
    }
}

// ---------------- k4: per-batch quadrature reduce + combine (wave per batch) ----------------
__global__ void k4_final(const float* __restrict__ x, const float* __restrict__ fvals,
                         const float* __restrict__ offs, const float* __restrict__ scal,
                         float* __restrict__ out) {
    int tid = threadIdx.x;
    int wv = tid >> 6, lane = tid & 63;
    int b = blockIdx.x * 4 + wv;
    float v = (lane < 51) ? fvals[b * 51 + lane] : 0.f;   // fvals already cc-weighted
    #pragma unroll
    for (int mask = 1; mask < 64; mask <<= 1) v += __shfl_xor(v, mask, 64);
    if (lane == 0)
        out[b] = scal[b] * (0.5f * x[b] * v) + offs[b];
}

extern "C" void kernel_launch(void* const* d_in, const int* in_sizes, int n_in,
                              void* d_out, int out_size, void* d_ws, size_t ws_size,
                              hipStream_t stream) {
    const float* x   = (const float*)d_in[0];
    const float* h   = (const float*)d_in[1];
    const float* iw1 = (const float*)d_in[2];
    const float* ib1 = (const float*)d_in[3];
    const float* iw2 = (const float*)d_in[4];
    const float* ib2 = (const float*)d_in[5];
    const float* iw3 = (const float*)d_in[6];
    const float* ib3 = (const float*)d_in[7];
    const float* nw1 = (const float*)d_in[8];
    const float* nb1 = (const float*)d_in[9];
    const float* nw2 = (const float*)d_in[10];
    const float* nb2 = (const float*)d_in[11];
    const float* nw3 = (const float*)d_in[12];
    const float* nb3 = (const float*)d_in[13];
    float* out = (float*)d_out;

    char* ws = (char*)d_ws;
    unsigned short* iw2b = (unsigned short*)(ws + OFF_IW2B);
    unsigned short* nw2b = (unsigned short*)(ws + OFF_NW2B);
    float* w1xs  = (float*)(ws + OFF_W1X);
    float* cc    = (float*)(ws + OFF_CC);
    float* steps = (float*)(ws + OFF_STEPS);
    float* offs  = (float*)(ws + OFF_OFFS);
    float* scal  = (float*)(ws + OFF_SCAL);
    float* nw1p  = (float*)(ws + OFF_NW1P);
    float* g1    = (float*)(ws + OFF_G1);
    unsigned short* a1n = (unsigned short*)(ws + OFF_A1N);
    float* fvals = (float*)(ws + OFF_FVALS);   // aliases a1n; safe: k3 before k2

    k0_prep<<<dim3(259), dim3(256), 0, stream>>>(iw2, nw2, nw1, iw1, iw2b, nw2b, w1xs,
                                                 cc, steps, nw1p);
    k1_pre<<<dim3(BATCH / 4), dim3(256), 0, stream>>>(h, iw1, ib1, nw1p, nb1, g1, a1n);
    k3_nnet<<<dim3(BATCH / 64), dim3(256), 0, stream>>>(a1n, nw2b, nb2, nw3, nb3, offs, scal);
    k2_main<<<dim3(MTOT / 128), dim3(256), 0, stream>>>(x, g1, w1xs, iw2b, ib2, iw3, ib3,
                                                        cc, steps, fvals);
    k4_final<<<dim3(BATCH / 4), dim3(256), 0, stream>>>(x, fvals, offs, scal, out);
}